// Round 1
// baseline (1018.028 us; speedup 1.0000x reference)
//
#include <hip/hip_runtime.h>
#include <stdint.h>

#define BATCH   8
#define NITEMS  1000000
#define NBINS   262144        // 2^18 bins, bin = float_bits >> 14
#define CHUNK   1024
#define NCHUNK  (NBINS / CHUNK)   // 256
#define CAP     16384         // per-batch candidate capacity
#define IMG_W   768.0f
#define IMG_H   432.0f

static __device__ __forceinline__ float clip0(float v, float hi) {
    return fminf(fmaxf(v, 0.0f), hi);
}

// ---------------- kernel 0: zero histogram + meta ----------------
__global__ void k_zero(unsigned* __restrict__ hist,
                       unsigned* __restrict__ bb,
                       unsigned* __restrict__ candTotal) {
    int idx = blockIdx.x * blockDim.x + threadIdx.x;
    int total = BATCH * NBINS;
    for (int i = idx; i < total; i += gridDim.x * blockDim.x) hist[i] = 0u;
    if (idx < BATCH) { bb[idx] = 0u; candTotal[idx] = 0u; }
}

// ---------------- kernel 1: masked score bits + histogram ----------------
__global__ void k_bits_hist(const float* __restrict__ scores,
                            const float4* __restrict__ rps,
                            unsigned* __restrict__ bits_arr,
                            unsigned* __restrict__ hist) {
    const int b = blockIdx.y;
    const int base = b * NITEMS;
    unsigned* h = hist + b * NBINS;
    for (int i = blockIdx.x * blockDim.x + threadIdx.x; i < NITEMS;
         i += gridDim.x * blockDim.x) {
        const int j = base + i;
        float4 box = rps[j];
        float s = scores[j];
        float x1 = clip0(box.x - box.z * 0.5f, IMG_W);
        float x2 = clip0(box.x + box.z * 0.5f, IMG_W);
        float y1 = clip0(box.y - box.w * 0.5f, IMG_H);
        float y2 = clip0(box.y + box.w * 0.5f, IMG_H);
        float nw = x2 - x1, nh = y2 - y1;
        bool m = (nw > 16.0f) && (nh > 16.0f);
        float sm = m ? s : 0.0f;
        unsigned bits = __float_as_uint(sm);
        bits_arr[j] = bits;
        if (bits) atomicAdd(&h[bits >> 14], 1u);
    }
}

// ---------------- kernel 2a: per-chunk sums ----------------
__global__ void k_chunksum(const unsigned* __restrict__ hist,
                           unsigned* __restrict__ chunkSum) {
    const int b = blockIdx.y, c = blockIdx.x;
    const unsigned* h = hist + b * NBINS + c * CHUNK;
    __shared__ unsigned red[256];
    unsigned s = 0;
    for (int i = threadIdx.x; i < CHUNK; i += 256) s += h[i];
    red[threadIdx.x] = s;
    __syncthreads();
    for (int off = 128; off > 0; off >>= 1) {
        if (threadIdx.x < off) red[threadIdx.x] += red[threadIdx.x + off];
        __syncthreads();
    }
    if (threadIdx.x == 0) chunkSum[b * NCHUNK + c] = red[0];
}

// ---------------- kernel 2b: suffix-scan chunk sums ----------------
__global__ void k_chunkscan(const unsigned* __restrict__ chunkSum,
                            unsigned* __restrict__ chunkBase) {
    const int b = blockIdx.x;
    const int tid = threadIdx.x;           // r = tid (reversed order)
    __shared__ unsigned v[NCHUNK];
    unsigned own = chunkSum[b * NCHUNK + (NCHUNK - 1 - tid)];
    v[tid] = own;
    __syncthreads();
    unsigned x = own;
    for (int off = 1; off < NCHUNK; off <<= 1) {
        unsigned t = (tid >= off) ? v[tid - off] : 0u;
        __syncthreads();
        x += t;
        v[tid] = x;
        __syncthreads();
    }
    // exclusive suffix: count of items in chunks strictly above
    chunkBase[b * NCHUNK + (NCHUNK - 1 - tid)] = x - own;
}

// ---------------- kernel 2c: per-bin suffix counts + boundary bin ----------------
__global__ void k_suffix(const unsigned* __restrict__ hist,
                         const unsigned* __restrict__ chunkBase,
                         unsigned* __restrict__ suffix,
                         unsigned* __restrict__ bb,
                         unsigned* __restrict__ candTotal,
                         int K) {
    const int b = blockIdx.y, c = blockIdx.x;
    const int tid = threadIdx.x;
    const unsigned* h = hist + b * NBINS;
    const int base = c * CHUNK;
    unsigned loc[4];
    unsigned tsum = 0;
    for (int k = 0; k < 4; k++) {
        int r = tid * 4 + k;                 // reversed within chunk
        int g = base + CHUNK - 1 - r;
        loc[k] = h[g];
        tsum += loc[k];
    }
    __shared__ unsigned v[256];
    v[tid] = tsum;
    __syncthreads();
    unsigned x = tsum;
    for (int off = 1; off < 256; off <<= 1) {
        unsigned t = (tid >= off) ? v[tid - off] : 0u;
        __syncthreads();
        x += t;
        v[tid] = x;
        __syncthreads();
    }
    unsigned running = chunkBase[b * NCHUNK + c] + (x - tsum);  // exclusive
    for (int k = 0; k < 4; k++) {
        int r = tid * 4 + k;
        int g = base + CHUNK - 1 - r;
        unsigned sfx = running;
        suffix[b * NBINS + g] = sfx;
        unsigned hh = loc[k];
        if (sfx < (unsigned)K && sfx + hh >= (unsigned)K) {
            bb[b] = (unsigned)g;             // unique crossing bin
            candTotal[b] = sfx + hh;
        }
        running += hh;
    }
}

// ---------------- kernel 3: compact candidates into bin segments ----------------
__global__ void k_compact(const unsigned* __restrict__ bits_arr,
                          unsigned* __restrict__ hist,        // destroyed (atomicSub)
                          const unsigned* __restrict__ suffix,
                          const unsigned* __restrict__ bb,
                          unsigned long long* __restrict__ cand) {
    const int b = blockIdx.y;
    const unsigned bound = bb[b];
    const int base = b * NITEMS;
    for (int i = blockIdx.x * blockDim.x + threadIdx.x; i < NITEMS;
         i += gridDim.x * blockDim.x) {
        unsigned bits = bits_arr[base + i];
        if (!bits) continue;
        unsigned g = bits >> 14;
        if (g < bound) continue;
        unsigned pos = atomicSub(&hist[b * NBINS + g], 1u) - 1u;
        unsigned slot = suffix[b * NBINS + g] + pos;
        if (slot < CAP) {
            cand[b * CAP + slot] =
                ((unsigned long long)bits << 32) | (unsigned)(~(unsigned)i);
        }
    }
}

// ---------------- kernel 4: rank within segment, gather, write outputs ----------------
#define TILE 1024
__global__ void k_rank_out(const unsigned long long* __restrict__ cand,
                           const unsigned* __restrict__ suffix,
                           const unsigned* __restrict__ candTotal,
                           const float4* __restrict__ rps,
                           float* __restrict__ out,
                           int K) {
    const int b = blockIdx.y;
    const unsigned total = candTotal[b];
    const unsigned P0 = blockIdx.x * blockDim.x;
    if (P0 >= total) return;
    const int tid = threadIdx.x;
    const unsigned p = P0 + (unsigned)tid;
    const bool active = (p < total);

    unsigned long long key = 0ull;
    unsigned sbase = 0, send = 0;
    if (active) {
        key = cand[b * CAP + p];
        unsigned g = (unsigned)(key >> 46);             // = bits >> 14
        sbase = suffix[b * NBINS + g];
        send  = (g > 0) ? suffix[b * NBINS + g - 1] : total;
    }
    __shared__ unsigned u0s, u1s;
    __shared__ unsigned long long tile[TILE];
    unsigned lastActive = total - 1u - P0;
    if (lastActive > (unsigned)(blockDim.x - 1)) lastActive = blockDim.x - 1;
    if (tid == 0) u0s = sbase;                          // min over block (monotone)
    if (tid == (int)lastActive) u1s = send;             // max over block (monotone)
    __syncthreads();
    const unsigned U0 = u0s, U1 = u1s;

    unsigned rank = 0;
    for (unsigned t0 = U0; t0 < U1; t0 += TILE) {
        unsigned tend = t0 + TILE; if (tend > U1) tend = U1;
        for (unsigned i = t0 + tid; i < tend; i += blockDim.x)
            tile[i - t0] = cand[b * CAP + i];
        __syncthreads();
        if (active) {
            unsigned lo = (t0 > sbase) ? t0 : sbase;
            unsigned hi = (tend < send) ? tend : send;
            for (unsigned i = lo; i < hi; ++i)
                rank += (tile[i - t0] > key) ? 1u : 0u;
        }
        __syncthreads();
    }

    if (active) {
        unsigned fin = sbase + rank;                    // global descending rank
        if (fin < (unsigned)K) {
            unsigned idx = ~((unsigned)key);
            float s = __uint_as_float((unsigned)(key >> 32));
            float4 box = rps[b * NITEMS + (int)idx];
            float x1 = clip0(box.x - box.z * 0.5f, IMG_W);
            float x2 = clip0(box.x + box.z * 0.5f, IMG_W);
            float y1 = clip0(box.y - box.w * 0.5f, IMG_H);
            float y2 = clip0(box.y + box.w * 0.5f, IMG_H);
            float nw = x2 - x1, nh = y2 - y1;
            float nx = x1 + nw * 0.5f, ny = y1 + nh * 0.5f;
            ((float4*)out)[(size_t)b * K + fin] = make_float4(nx, ny, nw, nh);
            out[(size_t)BATCH * K * 4 + (size_t)b * K + fin] = s;
        }
    }
}

extern "C" void kernel_launch(void* const* d_in, const int* in_sizes, int n_in,
                              void* d_out, int out_size, void* d_ws, size_t ws_size,
                              hipStream_t stream) {
    const float*  scores = (const float*)d_in[0];
    const float4* rps    = (const float4*)d_in[1];
    const int K = out_size / (BATCH * 5);               // 12000 for this problem

    uint8_t* w = (uint8_t*)d_ws;
    unsigned* bits_arr           = (unsigned*)(w);                         // 32.0e6 B
    unsigned* hist               = (unsigned*)(w + ((size_t)32 << 20));    // 8 MiB
    unsigned* suffix             = (unsigned*)(w + ((size_t)40 << 20));    // 8 MiB
    unsigned long long* cand     = (unsigned long long*)(w + ((size_t)48 << 20)); // 1 MiB
    unsigned* chunkSum           = (unsigned*)(w + ((size_t)49 << 20));    // 8 KiB
    unsigned* chunkBase          = chunkSum + BATCH * NCHUNK;              // 8 KiB
    unsigned* bb                 = chunkBase + BATCH * NCHUNK;
    unsigned* candTotal          = bb + BATCH;

    k_zero<<<dim3(2048), dim3(256), 0, stream>>>(hist, bb, candTotal);
    k_bits_hist<<<dim3(512, BATCH), dim3(256), 0, stream>>>(scores, rps, bits_arr, hist);
    k_chunksum<<<dim3(NCHUNK, BATCH), dim3(256), 0, stream>>>(hist, chunkSum);
    k_chunkscan<<<dim3(BATCH), dim3(NCHUNK), 0, stream>>>(chunkSum, chunkBase);
    k_suffix<<<dim3(NCHUNK, BATCH), dim3(256), 0, stream>>>(hist, chunkBase, suffix,
                                                            bb, candTotal, K);
    k_compact<<<dim3(512, BATCH), dim3(256), 0, stream>>>(bits_arr, hist, suffix, bb, cand);
    k_rank_out<<<dim3(CAP / 256, BATCH), dim3(256), 0, stream>>>(cand, suffix, candTotal,
                                                                 rps, (float*)d_out, K);
}

// Round 2
// 103.727 us; speedup vs baseline: 9.8145x; 9.8145x over previous
//
#include <hip/hip_runtime.h>
#include <stdint.h>

#define BATCH   8
#define NITEMS  1000000
#define NB      4096          // bins for both coarse (bits>>20) and fine ((bits>>8)&0xFFF)
#define NBLK    64            // blocks per batch for streaming passes
#define CAP     32768         // per-batch candidate capacity
#define IMG_W   768.0f
#define IMG_H   432.0f

static __device__ __forceinline__ float clip0(float v, float hi) {
    return fminf(fmaxf(v, 0.0f), hi);
}

// ---------------- kernel 0: zero counters + meta ----------------
__global__ void k_zero(unsigned* __restrict__ ctrA,
                       unsigned* __restrict__ ctrB,
                       unsigned* __restrict__ meta) {
    int idx = blockIdx.x * blockDim.x + threadIdx.x;
    int total = BATCH * NB;
    for (int i = idx; i < total; i += gridDim.x * blockDim.x) {
        ctrA[i] = 0u;
        ctrB[i] = 0u;
    }
    if (idx < BATCH * 4) meta[idx] = 0u;
}

// ---------------- kernel 1: masked score bits + coarse LDS histogram ----------------
__global__ __launch_bounds__(512)
void k_bits_hist(const float* __restrict__ scores,
                 const float4* __restrict__ rps,
                 unsigned* __restrict__ bits_arr,
                 unsigned* __restrict__ partial) {
    __shared__ unsigned h[NB];
    const int b = blockIdx.y, blk = blockIdx.x, tid = threadIdx.x;
    for (int k = tid; k < NB; k += 512) h[k] = 0u;
    __syncthreads();
    const int base = b * NITEMS;
    for (int i = blk * 512 + tid; i < NITEMS; i += NBLK * 512) {
        float4 box = rps[base + i];
        float s = scores[base + i];
        float x1 = clip0(box.x - box.z * 0.5f, IMG_W);
        float x2 = clip0(box.x + box.z * 0.5f, IMG_W);
        float y1 = clip0(box.y - box.w * 0.5f, IMG_H);
        float y2 = clip0(box.y + box.w * 0.5f, IMG_H);
        float nw = x2 - x1, nh = y2 - y1;
        bool m = (nw > 16.0f) && (nh > 16.0f);
        unsigned bits = __float_as_uint(m ? s : 0.0f);
        bits_arr[base + i] = bits;
        if (bits) atomicAdd(&h[bits >> 20], 1u);
    }
    __syncthreads();
    unsigned* dst = partial + ((size_t)(b * NBLK + blk)) * NB;
    for (int k = tid; k < NB; k += 512) dst[k] = h[k];
}

// ---------------- kernel 2: fine LDS histogram of boundary coarse bin ----------------
__global__ __launch_bounds__(512)
void k_fine_hist(const unsigned* __restrict__ bits_arr,
                 const unsigned* __restrict__ meta,
                 unsigned* __restrict__ partial) {
    __shared__ unsigned h[NB];
    const int b = blockIdx.y, blk = blockIdx.x, tid = threadIdx.x;
    const unsigned cbb = meta[b * 4 + 0];
    for (int k = tid; k < NB; k += 512) h[k] = 0u;
    __syncthreads();
    const int base = b * NITEMS;
    for (int i = blk * 512 + tid; i < NITEMS; i += NBLK * 512) {
        unsigned bits = bits_arr[base + i];
        if (bits && (bits >> 20) == cbb) atomicAdd(&h[(bits >> 8) & 0xFFF], 1u);
    }
    __syncthreads();
    unsigned* dst = partial + ((size_t)(b * NBLK + blk)) * NB;
    for (int k = tid; k < NB; k += 512) dst[k] = h[k];
}

// ---------------- reduce: sum per-block partial hists ----------------
__global__ __launch_bounds__(256)
void k_reduce(const unsigned* __restrict__ partial,
              unsigned* __restrict__ hist) {
    const int b = blockIdx.y;
    const int g = blockIdx.x * 256 + threadIdx.x;    // grid.x = NB/256
    const unsigned* p = partial + (size_t)b * NBLK * NB + g;
    unsigned s = 0;
    for (int k = 0; k < NBLK; k++) s += p[(size_t)k * NB];
    hist[b * NB + g] = s;
}

// ---------------- suffix scan over 4096 bins; find boundary bin ----------------
// mode 0: coarse -> meta[0]=cbb, meta[1]=nAbove
// mode 1: fine   -> meta[2]=fb,  meta[3]=candTotal   (offset by nAbove)
__global__ __launch_bounds__(1024)
void k_scan(const unsigned* __restrict__ hist,
            unsigned* __restrict__ suffix,
            unsigned* __restrict__ meta,
            int K, int mode) {
    const int b = blockIdx.x, tid = threadIdx.x;
    __shared__ unsigned lh[NB];
    __shared__ unsigned sc[1024];
    const unsigned* h = hist + b * NB;
    for (int k = tid; k < NB; k += 1024) lh[k] = h[k];
    __syncthreads();
    unsigned c[4], p[4];
    unsigned run = 0;
    for (int k = 0; k < 4; k++) {
        int r = tid * 4 + k;                  // reversed index
        c[k] = lh[NB - 1 - r];
        run += c[k];
        p[k] = run;                           // inclusive within thread
    }
    sc[tid] = run;
    __syncthreads();
    unsigned x = run;
    for (int off = 1; off < 1024; off <<= 1) {
        unsigned t = (tid >= off) ? sc[tid - off] : 0u;
        __syncthreads();
        x += t;
        sc[tid] = x;
        __syncthreads();
    }
    unsigned exclBase = x - run;
    unsigned off0 = mode ? meta[b * 4 + 1] : 0u;   // nAbove for fine pass
    for (int k = 0; k < 4; k++) {
        int r = tid * 4 + k;
        int g = NB - 1 - r;
        unsigned excl = exclBase + p[k] - c[k];    // count strictly above bin g
        suffix[b * NB + g] = excl;
        unsigned tot = off0 + excl;
        if (tot < (unsigned)K && tot + c[k] >= (unsigned)K) {
            if (mode == 0) {
                meta[b * 4 + 0] = (unsigned)g;     // cbb
                meta[b * 4 + 1] = excl;            // nAbove
            } else {
                meta[b * 4 + 2] = (unsigned)g;     // fb
                meta[b * 4 + 3] = tot + c[k];      // candTotal
            }
        }
    }
}

// ---------------- compact candidates into segmented slots ----------------
__global__ __launch_bounds__(512)
void k_compact(const unsigned* __restrict__ bits_arr,
               const unsigned* __restrict__ meta,
               const unsigned* __restrict__ csuf,
               const unsigned* __restrict__ fsuf,
               unsigned* __restrict__ ctrA,
               unsigned* __restrict__ ctrB,
               unsigned long long* __restrict__ cand) {
    const int b = blockIdx.y;
    const unsigned cbb = meta[b * 4 + 0];
    const unsigned nAbove = meta[b * 4 + 1];
    const unsigned fb = meta[b * 4 + 2];
    const int base = b * NITEMS;
    for (int i = blockIdx.x * 512 + threadIdx.x; i < NITEMS; i += NBLK * 512) {
        unsigned bits = bits_arr[base + i];
        if (!bits) continue;
        unsigned cb = bits >> 20;
        if (cb < cbb) continue;
        unsigned slot;
        if (cb > cbb) {
            slot = csuf[b * NB + cb] + atomicAdd(&ctrA[b * NB + cb], 1u);
        } else {
            unsigned f = (bits >> 8) & 0xFFF;
            if (f < fb) continue;
            slot = nAbove + fsuf[b * NB + f] + atomicAdd(&ctrB[b * NB + f], 1u);
        }
        if (slot < CAP)
            cand[(size_t)b * CAP + slot] =
                ((unsigned long long)bits << 32) | (unsigned)(~(unsigned)i);
    }
}

// ---------------- rank within (tiny) segment, gather, write outputs ----------------
__global__ __launch_bounds__(256)
void k_rank_out(const unsigned long long* __restrict__ cand,
                const unsigned* __restrict__ meta,
                const unsigned* __restrict__ csuf,
                const unsigned* __restrict__ chist,
                const unsigned* __restrict__ fsuf,
                const unsigned* __restrict__ fhist,
                const float4* __restrict__ rps,
                float* __restrict__ out,
                int K) {
    const int b = blockIdx.y;
    unsigned total = meta[b * 4 + 3];
    if (total > CAP) total = CAP;
    const unsigned p = blockIdx.x * 256 + threadIdx.x;
    if (p >= total) return;
    const unsigned long long key = cand[(size_t)b * CAP + p];
    const unsigned bits = (unsigned)(key >> 32);
    const unsigned cb = bits >> 20;
    const unsigned cbb = meta[b * 4 + 0];
    const unsigned nAbove = meta[b * 4 + 1];
    unsigned sbase, scnt;
    if (cb > cbb) {
        sbase = csuf[b * NB + cb];
        scnt  = chist[b * NB + cb];
    } else {
        unsigned f = (bits >> 8) & 0xFFF;
        sbase = nAbove + fsuf[b * NB + f];
        scnt  = fhist[b * NB + f];
    }
    unsigned send = sbase + scnt;
    if (send > total) send = total;
    unsigned rank = sbase;
    for (unsigned j = sbase; j < send; j++)
        rank += (cand[(size_t)b * CAP + j] > key) ? 1u : 0u;
    if (rank < (unsigned)K) {
        unsigned idx = ~((unsigned)key);
        float s = __uint_as_float(bits);
        float4 box = rps[(size_t)b * NITEMS + idx];
        float x1 = clip0(box.x - box.z * 0.5f, IMG_W);
        float x2 = clip0(box.x + box.z * 0.5f, IMG_W);
        float y1 = clip0(box.y - box.w * 0.5f, IMG_H);
        float y2 = clip0(box.y + box.w * 0.5f, IMG_H);
        float nw = x2 - x1, nh = y2 - y1;
        float nx = x1 + nw * 0.5f, ny = y1 + nh * 0.5f;
        ((float4*)out)[(size_t)b * K + rank] = make_float4(nx, ny, nw, nh);
        out[(size_t)BATCH * K * 4 + (size_t)b * K + rank] = s;
    }
}

extern "C" void kernel_launch(void* const* d_in, const int* in_sizes, int n_in,
                              void* d_out, int out_size, void* d_ws, size_t ws_size,
                              hipStream_t stream) {
    const float*  scores = (const float*)d_in[0];
    const float4* rps    = (const float4*)d_in[1];
    const int K = out_size / (BATCH * 5);               // 12000

    uint8_t* w = (uint8_t*)d_ws;
    unsigned* bits_arr = (unsigned*)(w);                        // 32,000,000 B
    unsigned* partial  = (unsigned*)(w + 32000000);             // 8,388,608 B
    unsigned* chist    = (unsigned*)(w + 40400000);             // 131,072 B
    unsigned* csuf     = (unsigned*)(w + 40600000);             // 131,072 B
    unsigned* fhist    = (unsigned*)(w + 40800000);             // 131,072 B
    unsigned* fsuf     = (unsigned*)(w + 41000000);             // 131,072 B
    unsigned* ctrA     = (unsigned*)(w + 41200000);             // 131,072 B
    unsigned* ctrB     = (unsigned*)(w + 41400000);             // 131,072 B
    unsigned* meta     = (unsigned*)(w + 41600000);             // 128 B
    unsigned long long* cand = (unsigned long long*)(w + 41700000); // 2,097,152 B

    k_zero<<<dim3(256), dim3(256), 0, stream>>>(ctrA, ctrB, meta);
    k_bits_hist<<<dim3(NBLK, BATCH), dim3(512), 0, stream>>>(scores, rps, bits_arr, partial);
    k_reduce<<<dim3(NB / 256, BATCH), dim3(256), 0, stream>>>(partial, chist);
    k_scan<<<dim3(BATCH), dim3(1024), 0, stream>>>(chist, csuf, meta, K, 0);
    k_fine_hist<<<dim3(NBLK, BATCH), dim3(512), 0, stream>>>(bits_arr, meta, partial);
    k_reduce<<<dim3(NB / 256, BATCH), dim3(256), 0, stream>>>(partial, fhist);
    k_scan<<<dim3(BATCH), dim3(1024), 0, stream>>>(fhist, fsuf, meta, K, 1);
    k_compact<<<dim3(NBLK, BATCH), dim3(512), 0, stream>>>(bits_arr, meta, csuf, fsuf,
                                                           ctrA, ctrB, cand);
    k_rank_out<<<dim3(CAP / 256, BATCH), dim3(256), 0, stream>>>(cand, meta, csuf, chist,
                                                                 fsuf, fhist, rps,
                                                                 (float*)d_out, K);
}